// Round 9
// baseline (834.974 us; speedup 1.0000x reference)
//
#include <hip/hip_runtime.h>

#define BB 2
#define NN 32768
#define KK 16
#define DD 64
#define NC 10
#define NMOM 65
#define NBLK1 256
#define BN_EPS 1e-6

__host__ __device__ __forceinline__ constexpr int pair_idx(int i, int j) {
    return 10 + i * 10 - (i * (i - 1)) / 2 + (j - i);
}

// ---------------- Kernel 1: concat-vector moment reduction ----------------
__global__ __launch_bounds__(256) void k_moments(
    const float* __restrict__ coords, const float* __restrict__ dist,
    const int* __restrict__ idx, float* __restrict__ partials)
{
    const int tid = threadIdx.x;
    const int bn = blockIdx.x * 256 + tid;
    const int b = bn >> 15;

    float acc[NMOM];
#pragma unroll
    for (int v = 0; v < NMOM; ++v) acc[v] = 0.f;

    const float cx = coords[(size_t)bn * 3 + 0];
    const float cy = coords[(size_t)bn * 3 + 1];
    const float cz = coords[(size_t)bn * 3 + 2];
    const float* cb = coords + (size_t)b * NN * 3;

    for (int k = 0; k < KK; ++k) {
        const int j = idx[(size_t)bn * KK + k];
        const float nx = cb[(size_t)j * 3 + 0];
        const float ny = cb[(size_t)j * 3 + 1];
        const float nz = cb[(size_t)j * 3 + 2];
        const float dd = dist[(size_t)bn * KK + k];
        const float c[NC] = {cx, cy, cz, nx, ny, nz, cx - nx, cy - ny, cz - nz, dd};
#pragma unroll
        for (int i = 0; i < NC; ++i) acc[i] += c[i];
#pragma unroll
        for (int i = 0; i < NC; ++i)
#pragma unroll
            for (int jj = i; jj < NC; ++jj)
                acc[pair_idx(i, jj)] += c[i] * c[jj];
    }

    __shared__ float red[4 * NMOM];
    const int lane = tid & 63, wave = tid >> 6;
#pragma unroll
    for (int v = 0; v < NMOM; ++v) {
        float x = acc[v];
        x += __shfl_down(x, 32);
        x += __shfl_down(x, 16);
        x += __shfl_down(x, 8);
        x += __shfl_down(x, 4);
        x += __shfl_down(x, 2);
        x += __shfl_down(x, 1);
        if (lane == 0) red[wave * NMOM + v] = x;
    }
    __syncthreads();
    if (tid < NMOM) {
        float p = red[tid] + red[NMOM + tid] + red[2 * NMOM + tid] + red[3 * NMOM + tid];
        partials[blockIdx.x * NMOM + tid] = p;
    }
}

// ---------------- Kernel 2: finalize BN stats, fold into w/bias ----------------
__global__ __launch_bounds__(320) void k_finalize(
    const float* __restrict__ partials,
    const float* __restrict__ conv_w, const float* __restrict__ conv_b,
    const float* __restrict__ gamma, const float* __restrict__ beta,
    float* __restrict__ wscaled, float* __restrict__ bias2)
{
    __shared__ double part[4][NMOM];
    __shared__ double sums[NMOM];
    const int tid = threadIdx.x;
    const int g = tid / NMOM, m = tid % NMOM;
    if (g < 4) {
        double s = 0.0;
        for (int blk = g * 64; blk < (g + 1) * 64; ++blk)
            s += (double)partials[blk * NMOM + m];
        part[g][m] = s;
    }
    __syncthreads();
    if (tid < NMOM)
        sums[tid] = part[0][tid] + part[1][tid] + part[2][tid] + part[3][tid];
    __syncthreads();
    if (tid < DD) {
        const double cnt = (double)BB * NN * KK;
        double mm[NC], w[NC];
#pragma unroll
        for (int c = 0; c < NC; ++c) {
            mm[c] = sums[c] / cnt;
            w[c] = (double)conv_w[tid * NC + c];
        }
        const double bd = (double)conv_b[tid];
        double wm = 0.0;
#pragma unroll
        for (int c = 0; c < NC; ++c) wm += w[c] * mm[c];
        const double mean = wm + bd;
        double ex2 = bd * bd + 2.0 * bd * wm;
#pragma unroll
        for (int i = 0; i < NC; ++i)
#pragma unroll
            for (int j = i; j < NC; ++j) {
                const double Mij = sums[pair_idx(i, j)] / cnt;
                ex2 += (i == j ? 1.0 : 2.0) * w[i] * w[j] * Mij;
            }
        const double var = ex2 - mean * mean;
        const double scale = (double)gamma[tid] / sqrt(var + BN_EPS);
        bias2[tid] = (float)((double)beta[tid] + (bd - mean) * scale);
#pragma unroll
        for (int c = 0; c < NC; ++c)
            wscaled[tid * NC + c] = (float)(w[c] * scale);
    }
}

// ---------------- Kernel 3: unified output, monotonic front, recompute c ----
// Block = one contiguous 16 KiB output chunk: (b, ch2, nc), nc FASTEST ->
// blockIdx monotonic in output address (single global write front).
// x-blocks (ch2 < 64): thread owns one n (all 16 k); gathers its 16
// neighbors, applies the algebraically folded conv+BN+relu (4 FMA/element):
//   x = s_cen + (w_nbr - w_diff)·nbr + w_dist*dist
// feat-blocks (ch2 >= 64): broadcast features (R8 path, proven ~4.7 TB/s).
__global__ __launch_bounds__(256) void k_out(
    const float* __restrict__ coords, const float* __restrict__ features,
    const float* __restrict__ dist, const int* __restrict__ idx,
    const float* __restrict__ wscaled, const float* __restrict__ bias2,
    float* __restrict__ out)
{
    const int nc  = blockIdx.x & 127;            // 128 chunks of 256 n (fastest)
    const int ch2 = (blockIdx.x >> 7) & 127;
    const int b   = blockIdx.x >> 14;
    const int tid = threadIdx.x;
    const size_t plane = ((size_t)b * 2 * DD + ch2) * ((size_t)NN * KK);

    if (ch2 < DD) {
        const int d = ch2;                        // block-uniform -> scalar loads
        float wv[NC];
#pragma unroll
        for (int ch = 0; ch < NC; ++ch) wv[ch] = wscaled[d * NC + ch];
        const float b2 = bias2[d];

        const int n = nc * 256 + tid;
        const int bn = b * NN + n;
        const float* cc = coords + (size_t)bn * 3;
        const float cx = cc[0], cy = cc[1], cz = cc[2];
        const float* cb = coords + (size_t)b * NN * 3;

        // fold: x = b2 + (w0+w6)cx + (w1+w7)cy + (w2+w8)cz
        //           + (w3-w6)nx + (w4-w7)ny + (w5-w8)nz + w9*dist
        const float s_cen = b2 + (wv[0] + wv[6]) * cx + (wv[1] + wv[7]) * cy
                               + (wv[2] + wv[8]) * cz;
        const float a3 = wv[3] - wv[6], a4 = wv[4] - wv[7], a5 = wv[5] - wv[8];
        const float a9 = wv[9];

        const int4*   ip = reinterpret_cast<const int4*>(idx + (size_t)bn * KK);
        const float4* dp = reinterpret_cast<const float4*>(dist + (size_t)bn * KK);
        float* dst = out + plane + (size_t)n * KK;

#pragma unroll
        for (int kq = 0; kq < 4; ++kq) {
            const int4 j4 = ip[kq];
            const float4 d4 = dp[kq];
            const int js[4] = {j4.x, j4.y, j4.z, j4.w};
            const float dsv[4] = {d4.x, d4.y, d4.z, d4.w};
            float4 r;
            float* rp = reinterpret_cast<float*>(&r);
#pragma unroll
            for (int q = 0; q < 4; ++q) {
                const float* nb = cb + (size_t)js[q] * 3;
                const float v = s_cen + a3 * nb[0] + a4 * nb[1] + a5 * nb[2]
                                      + a9 * dsv[q];
                rp[q] = fmaxf(v, 0.f);
            }
            *reinterpret_cast<float4*>(dst + kq * 4) = r;
        }
    } else {
        const int d = ch2 - DD;
        const float* fb = features + ((size_t)b * DD + d) * NN;
        const size_t locbase = (size_t)nc * 256 * KK;
#pragma unroll
        for (int j = 0; j < 4; ++j) {
            const int q = j * 256 + tid;          // float4 index in chunk
            const int n = nc * 256 + (q >> 2);
            const float f = fb[n];
            *reinterpret_cast<float4*>(out + plane + locbase + (size_t)q * 4) =
                float4{f, f, f, f};
        }
    }
}

// ---------------- launch ----------------
extern "C" void kernel_launch(void* const* d_in, const int* in_sizes, int n_in,
                              void* d_out, int out_size, void* d_ws, size_t ws_size,
                              hipStream_t stream) {
    const float* coords   = (const float*)d_in[0];
    const float* features = (const float*)d_in[1];
    const float* dist     = (const float*)d_in[2];
    const float* conv_w   = (const float*)d_in[3];
    const float* conv_b   = (const float*)d_in[4];
    const float* gamma    = (const float*)d_in[5];
    const float* beta     = (const float*)d_in[6];
    const int*   idx      = (const int*)d_in[7];
    float* out = (float*)d_out;

    float* partials = (float*)d_ws;                 // 256*65 floats
    float* wscaled  = partials + NBLK1 * NMOM;      // 640 floats
    float* bias2    = wscaled + DD * NC;            // 64 floats

    k_moments<<<NBLK1, 256, 0, stream>>>(coords, dist, idx, partials);
    k_finalize<<<1, 320, 0, stream>>>(partials, conv_w, conv_b, gamma, beta,
                                      wscaled, bias2);
    k_out<<<BB * 128 * 128, 256, 0, stream>>>(coords, features, dist, idx,
                                              wscaled, bias2, out);
}

// Round 10
// 687.937 us; speedup vs baseline: 1.2137x; 1.2137x over previous
//
#include <hip/hip_runtime.h>

#define BB 2
#define NN 32768
#define KK 16
#define DD 64
#define NC 10
#define NMOM 65
#define NBLK1 1024
#define BN_EPS 1e-6
#define BNK ((size_t)BB * NN * KK)   // 1,048,576

__host__ __device__ __forceinline__ constexpr int pair_idx(int i, int j) {
    return 10 + i * 10 - (i * (i - 1)) / 2 + (j - i);
}

// ---- Kernel 1: gather neighbors ONCE -> nbuf[3][BNK]; fused moment reduction
// thread = (bn, k-quad): 4 (n,k) pairs. Gather amp = 1 for the whole pipeline.
__global__ __launch_bounds__(256) void k_stage(
    const float* __restrict__ coords, const float* __restrict__ dist,
    const int* __restrict__ idx, float* __restrict__ nbuf,
    float* __restrict__ partials)
{
    const int tid = threadIdx.x;
    const int q = blockIdx.x * 256 + tid;   // quad id
    const int e0 = q << 2;
    const int bn = e0 >> 4;
    const int k0 = e0 & 15;
    const int b = bn >> 15;

    const float* cc = coords + (size_t)bn * 3;
    const float cx = cc[0], cy = cc[1], cz = cc[2];
    const float* cb = coords + (size_t)b * NN * 3;

    const int4 j4 = *reinterpret_cast<const int4*>(idx + e0);
    const float4 d4 = *reinterpret_cast<const float4*>(dist + e0);
    const int js[4] = {j4.x, j4.y, j4.z, j4.w};
    const float dsv[4] = {d4.x, d4.y, d4.z, d4.w};

    float c[4][NC];
#pragma unroll
    for (int p = 0; p < 4; ++p) {
        const float* nb = cb + (size_t)js[p] * 3;
        const float nx = nb[0], ny = nb[1], nz = nb[2];
        c[p][0] = cx; c[p][1] = cy; c[p][2] = cz;
        c[p][3] = nx; c[p][4] = ny; c[p][5] = nz;
        c[p][6] = cx - nx; c[p][7] = cy - ny; c[p][8] = cz - nz;
        c[p][9] = dsv[p];
    }
    // stage neighbor coords, transposed [ch][e]
#pragma unroll
    for (int ch = 0; ch < 3; ++ch) {
        float4 v{c[0][3 + ch], c[1][3 + ch], c[2][3 + ch], c[3][3 + ch]};
        *reinterpret_cast<float4*>(&nbuf[(size_t)ch * BNK + e0]) = v;
    }

    // moments over this thread's 4 (n,k)
    float acc[NMOM];
#pragma unroll
    for (int v = 0; v < NMOM; ++v) acc[v] = 0.f;
#pragma unroll
    for (int p = 0; p < 4; ++p) {
#pragma unroll
        for (int i = 0; i < NC; ++i) acc[i] += c[p][i];
#pragma unroll
        for (int i = 0; i < NC; ++i)
#pragma unroll
            for (int jj = i; jj < NC; ++jj)
                acc[pair_idx(i, jj)] += c[p][i] * c[p][jj];
    }

    __shared__ float red[4 * NMOM];
    const int lane = tid & 63, wave = tid >> 6;
#pragma unroll
    for (int v = 0; v < NMOM; ++v) {
        float x = acc[v];
        x += __shfl_down(x, 32);
        x += __shfl_down(x, 16);
        x += __shfl_down(x, 8);
        x += __shfl_down(x, 4);
        x += __shfl_down(x, 2);
        x += __shfl_down(x, 1);
        if (lane == 0) red[wave * NMOM + v] = x;
    }
    __syncthreads();
    if (tid < NMOM) {
        float p = red[tid] + red[NMOM + tid] + red[2 * NMOM + tid] + red[3 * NMOM + tid];
        partials[blockIdx.x * NMOM + tid] = p;
    }
}

// ---- Kernel 2: finalize BN stats, fold into w/bias ----
__global__ __launch_bounds__(320) void k_finalize(
    const float* __restrict__ partials,
    const float* __restrict__ conv_w, const float* __restrict__ conv_b,
    const float* __restrict__ gamma, const float* __restrict__ beta,
    float* __restrict__ wscaled, float* __restrict__ bias2)
{
    __shared__ double part[4][NMOM];
    __shared__ double sums[NMOM];
    const int tid = threadIdx.x;
    const int g = tid / NMOM, m = tid % NMOM;
    if (g < 4) {
        double s = 0.0;
        for (int blk = g * 256; blk < (g + 1) * 256; ++blk)
            s += (double)partials[blk * NMOM + m];
        part[g][m] = s;
    }
    __syncthreads();
    if (tid < NMOM)
        sums[tid] = part[0][tid] + part[1][tid] + part[2][tid] + part[3][tid];
    __syncthreads();
    if (tid < DD) {
        const double cnt = (double)BB * NN * KK;
        double mm[NC], w[NC];
#pragma unroll
        for (int c = 0; c < NC; ++c) {
            mm[c] = sums[c] / cnt;
            w[c] = (double)conv_w[tid * NC + c];
        }
        const double bd = (double)conv_b[tid];
        double wm = 0.0;
#pragma unroll
        for (int c = 0; c < NC; ++c) wm += w[c] * mm[c];
        const double mean = wm + bd;
        double ex2 = bd * bd + 2.0 * bd * wm;
#pragma unroll
        for (int i = 0; i < NC; ++i)
#pragma unroll
            for (int j = i; j < NC; ++j) {
                const double Mij = sums[pair_idx(i, j)] / cnt;
                ex2 += (i == j ? 1.0 : 2.0) * w[i] * w[j] * Mij;
            }
        const double var = ex2 - mean * mean;
        const double scale = (double)gamma[tid] / sqrt(var + BN_EPS);
        bias2[tid] = (float)((double)beta[tid] + (bd - mean) * scale);
#pragma unroll
        for (int c = 0; c < NC; ++c)
            wscaled[tid * NC + c] = (float)(w[c] * scale);
    }
}

// ---- Kernel 3: unified output, monotonic 16KiB-chunk front, coalesced reads
// Block = (b, ch2, nc), nc FASTEST. x-blocks read staged nbr xyz + dist input
// (all coalesced, L2-resident per XCD) and apply the folded conv+BN+relu:
//   x = s_cen(n) + a3*nx + a4*ny + a5*nz + a9*dist
// feat-blocks broadcast features.
__global__ __launch_bounds__(256) void k_out(
    const float* __restrict__ coords, const float* __restrict__ features,
    const float* __restrict__ dist, const float* __restrict__ nbuf,
    const float* __restrict__ wscaled, const float* __restrict__ bias2,
    float* __restrict__ out)
{
    const int nc  = blockIdx.x & 127;            // 128 chunks of 256 n (fastest)
    const int ch2 = (blockIdx.x >> 7) & 127;
    const int b   = blockIdx.x >> 14;
    const int tid = threadIdx.x;
    const size_t plane = ((size_t)b * 2 * DD + ch2) * ((size_t)NN * KK);

    if (ch2 < DD) {
        const int d = ch2;                        // block-uniform -> scalar loads
        float wv[NC];
#pragma unroll
        for (int ch = 0; ch < NC; ++ch) wv[ch] = wscaled[d * NC + ch];
        const float b2 = bias2[d];

        const int n = nc * 256 + tid;
        const int bn = b * NN + n;
        const float* cc = coords + (size_t)bn * 3;
        const float s_cen = b2 + (wv[0] + wv[6]) * cc[0]
                               + (wv[1] + wv[7]) * cc[1]
                               + (wv[2] + wv[8]) * cc[2];
        const float a3 = wv[3] - wv[6], a4 = wv[4] - wv[7], a5 = wv[5] - wv[8];
        const float a9 = wv[9];

        const size_t e0 = (size_t)bn * KK;
        const float4* nxp = reinterpret_cast<const float4*>(nbuf + e0);
        const float4* nyp = reinterpret_cast<const float4*>(nbuf + BNK + e0);
        const float4* nzp = reinterpret_cast<const float4*>(nbuf + 2 * BNK + e0);
        const float4* dp  = reinterpret_cast<const float4*>(dist + e0);
        float* dst = out + plane + (size_t)n * KK;

#pragma unroll
        for (int kq = 0; kq < 4; ++kq) {
            const float4 nx = nxp[kq], ny = nyp[kq], nz = nzp[kq], dv = dp[kq];
            float4 r;
            r.x = fmaxf(s_cen + a3 * nx.x + a4 * ny.x + a5 * nz.x + a9 * dv.x, 0.f);
            r.y = fmaxf(s_cen + a3 * nx.y + a4 * ny.y + a5 * nz.y + a9 * dv.y, 0.f);
            r.z = fmaxf(s_cen + a3 * nx.z + a4 * ny.z + a5 * nz.z + a9 * dv.z, 0.f);
            r.w = fmaxf(s_cen + a3 * nx.w + a4 * ny.w + a5 * nz.w + a9 * dv.w, 0.f);
            *reinterpret_cast<float4*>(dst + kq * 4) = r;
        }
    } else {
        const int d = ch2 - DD;
        const float* fb = features + ((size_t)b * DD + d) * NN;
        const size_t locbase = (size_t)nc * 256 * KK;
#pragma unroll
        for (int j = 0; j < 4; ++j) {
            const int q = j * 256 + tid;          // float4 index in chunk
            const int n = nc * 256 + (q >> 2);
            const float f = fb[n];
            *reinterpret_cast<float4*>(out + plane + locbase + (size_t)q * 4) =
                float4{f, f, f, f};
        }
    }
}

// ---- launch ----
extern "C" void kernel_launch(void* const* d_in, const int* in_sizes, int n_in,
                              void* d_out, int out_size, void* d_ws, size_t ws_size,
                              hipStream_t stream) {
    const float* coords   = (const float*)d_in[0];
    const float* features = (const float*)d_in[1];
    const float* dist     = (const float*)d_in[2];
    const float* conv_w   = (const float*)d_in[3];
    const float* conv_b   = (const float*)d_in[4];
    const float* gamma    = (const float*)d_in[5];
    const float* beta     = (const float*)d_in[6];
    const int*   idx      = (const int*)d_in[7];
    float* out = (float*)d_out;

    float* partials = (float*)d_ws;                 // 1024*65 floats
    float* wscaled  = partials + NBLK1 * NMOM;      // 640 floats
    float* bias2    = wscaled + DD * NC;            // 64 floats
    float* nbuf     = (float*)d_ws + 131072;        // 3 * BNK floats = 12 MiB

    k_stage<<<(int)(BNK / 4 / 256), 256, 0, stream>>>(coords, dist, idx,
                                                      nbuf, partials);
    k_finalize<<<1, 320, 0, stream>>>(partials, conv_w, conv_b, gamma, beta,
                                      wscaled, bias2);
    k_out<<<BB * 128 * 128, 256, 0, stream>>>(coords, features, dist, nbuf,
                                              wscaled, bias2, out);
}

// Round 11
// 614.851 us; speedup vs baseline: 1.3580x; 1.1189x over previous
//
#include <hip/hip_runtime.h>

#define BB 2
#define NN 32768
#define KK 16
#define DD 64
#define NC 10
#define NMOM 65
#define NBLK1 256
#define BN_EPS 1e-6
#define DGRP 8              // d-planes per block in k_x (R7 anchor)
#define NCH 64              // n per block in k_x
#define NCHUNKS (NN / NCH)  // 512

__host__ __device__ __forceinline__ constexpr int pair_idx(int i, int j) {
    return 10 + i * 10 - (i * (i - 1)) / 2 + (j - i);
}

// ---- Kernel 0: pad coords to float4 (1 transaction per future gather) ----
__global__ __launch_bounds__(256) void k_coords4(
    const float* __restrict__ coords, float4* __restrict__ coords4)
{
    const int t = blockIdx.x * 256 + threadIdx.x;   // 0 .. B*N-1
    const float x = coords[(size_t)t * 3 + 0];
    const float y = coords[(size_t)t * 3 + 1];
    const float z = coords[(size_t)t * 3 + 2];
    coords4[t] = float4{x, y, z, 0.f};
}

// ---- Kernel 1: moment reduction (gathers via coords4, dwordx4) ----
__global__ __launch_bounds__(256) void k_moments(
    const float4* __restrict__ coords4, const float* __restrict__ dist,
    const int* __restrict__ idx, float* __restrict__ partials)
{
    const int tid = threadIdx.x;
    const int bn = blockIdx.x * 256 + tid;
    const int b = bn >> 15;

    float acc[NMOM];
#pragma unroll
    for (int v = 0; v < NMOM; ++v) acc[v] = 0.f;

    const float4 cen = coords4[bn];
    const float cx = cen.x, cy = cen.y, cz = cen.z;
    const float4* cb4 = coords4 + (size_t)b * NN;

    for (int k = 0; k < KK; ++k) {
        const int j = idx[(size_t)bn * KK + k];
        const float4 nb = cb4[j];
        const float dd = dist[(size_t)bn * KK + k];
        const float c[NC] = {cx, cy, cz, nb.x, nb.y, nb.z,
                             cx - nb.x, cy - nb.y, cz - nb.z, dd};
#pragma unroll
        for (int i = 0; i < NC; ++i) acc[i] += c[i];
#pragma unroll
        for (int i = 0; i < NC; ++i)
#pragma unroll
            for (int jj = i; jj < NC; ++jj)
                acc[pair_idx(i, jj)] += c[i] * c[jj];
    }

    __shared__ float red[4 * NMOM];
    const int lane = tid & 63, wave = tid >> 6;
#pragma unroll
    for (int v = 0; v < NMOM; ++v) {
        float x = acc[v];
        x += __shfl_down(x, 32);
        x += __shfl_down(x, 16);
        x += __shfl_down(x, 8);
        x += __shfl_down(x, 4);
        x += __shfl_down(x, 2);
        x += __shfl_down(x, 1);
        if (lane == 0) red[wave * NMOM + v] = x;
    }
    __syncthreads();
    if (tid < NMOM) {
        float p = red[tid] + red[NMOM + tid] + red[2 * NMOM + tid] + red[3 * NMOM + tid];
        partials[blockIdx.x * NMOM + tid] = p;
    }
}

// ---- Kernel 2: finalize BN stats; emit folded weights wfold[d][8] ----
// wfold = {wc_x,wc_y,wc_z, wn_x,wn_y,wn_z, w9, b2}:
//   x = b2 + wc·center + wn·neighbor + w9*dist
__global__ __launch_bounds__(320) void k_finalize(
    const float* __restrict__ partials,
    const float* __restrict__ conv_w, const float* __restrict__ conv_b,
    const float* __restrict__ gamma, const float* __restrict__ beta,
    float* __restrict__ wfold)
{
    __shared__ double part[4][NMOM];
    __shared__ double sums[NMOM];
    const int tid = threadIdx.x;
    const int g = tid / NMOM, m = tid % NMOM;
    if (g < 4) {
        double s = 0.0;
        for (int blk = g * 64; blk < (g + 1) * 64; ++blk)
            s += (double)partials[blk * NMOM + m];
        part[g][m] = s;
    }
    __syncthreads();
    if (tid < NMOM)
        sums[tid] = part[0][tid] + part[1][tid] + part[2][tid] + part[3][tid];
    __syncthreads();
    if (tid < DD) {
        const double cnt = (double)BB * NN * KK;
        double mm[NC], w[NC];
#pragma unroll
        for (int c = 0; c < NC; ++c) {
            mm[c] = sums[c] / cnt;
            w[c] = (double)conv_w[tid * NC + c];
        }
        const double bd = (double)conv_b[tid];
        double wm = 0.0;
#pragma unroll
        for (int c = 0; c < NC; ++c) wm += w[c] * mm[c];
        const double mean = wm + bd;
        double ex2 = bd * bd + 2.0 * bd * wm;
#pragma unroll
        for (int i = 0; i < NC; ++i)
#pragma unroll
            for (int j = i; j < NC; ++j) {
                const double Mij = sums[pair_idx(i, j)] / cnt;
                ex2 += (i == j ? 1.0 : 2.0) * w[i] * w[j] * Mij;
            }
        const double var = ex2 - mean * mean;
        const double scale = (double)gamma[tid] / sqrt(var + BN_EPS);
        const double b2 = (double)beta[tid] + (bd - mean) * scale;
        double ws[NC];
#pragma unroll
        for (int c = 0; c < NC; ++c) ws[c] = w[c] * scale;
        float* wf = wfold + tid * 8;
        wf[0] = (float)(ws[0] + ws[6]);
        wf[1] = (float)(ws[1] + ws[7]);
        wf[2] = (float)(ws[2] + ws[8]);
        wf[3] = (float)(ws[3] - ws[6]);
        wf[4] = (float)(ws[4] - ws[7]);
        wf[5] = (float)(ws[5] - ws[8]);
        wf[6] = (float)ws[9];
        wf[7] = (float)b2;
    }
}

// ---- Kernel 3: x-part (R7 write structure; dwordx4 gathers; folded math) ---
__global__ __launch_bounds__(256) void k_x(
    const float4* __restrict__ coords4, const float* __restrict__ dist,
    const int* __restrict__ idx, const float* __restrict__ wfold,
    float* __restrict__ out)
{
    const int nc   = blockIdx.x & (NCHUNKS - 1);          // fastest
    const int b    = (blockIdx.x >> 9) & 1;
    const int dgrp = blockIdx.x >> 10;                    // 0..7
    const int tid  = threadIdx.x;

    const int n_loc = tid >> 2;
    const int k0 = (tid & 3) << 2;
    const int n = nc * NCH + n_loc;
    const int bn = b * NN + n;

    const float4 cen = coords4[bn];
    const float4* cb4 = coords4 + (size_t)b * NN;

    const int4 j4 = *reinterpret_cast<const int4*>(idx + (size_t)bn * KK + k0);
    const float4 d4 = *reinterpret_cast<const float4*>(dist + (size_t)bn * KK + k0);
    const float4 nb0 = cb4[j4.x];
    const float4 nb1 = cb4[j4.y];
    const float4 nb2 = cb4[j4.z];
    const float4 nb3 = cb4[j4.w];

    const size_t cstride = (size_t)NN * KK;
    const size_t base = ((size_t)b * 2 * DD) * cstride + (size_t)n * KK + k0;

#pragma unroll
    for (int dd = 0; dd < DGRP; ++dd) {
        const int d = dgrp * DGRP + dd;
        const float4 f0 = *reinterpret_cast<const float4*>(wfold + d * 8);
        const float4 f1 = *reinterpret_cast<const float4*>(wfold + d * 8 + 4);
        // s_cen = b2 + wc·center (amortized over the 4 k)
        const float s_cen = f1.w + f0.x * cen.x + f0.y * cen.y + f0.z * cen.z;
        float4 r;
        r.x = fmaxf(s_cen + f0.w * nb0.x + f1.x * nb0.y + f1.y * nb0.z + f1.z * d4.x, 0.f);
        r.y = fmaxf(s_cen + f0.w * nb1.x + f1.x * nb1.y + f1.y * nb1.z + f1.z * d4.y, 0.f);
        r.z = fmaxf(s_cen + f0.w * nb2.x + f1.x * nb2.y + f1.y * nb2.z + f1.z * d4.z, 0.f);
        r.w = fmaxf(s_cen + f0.w * nb3.x + f1.x * nb3.y + f1.y * nb3.z + f1.z * d4.w, 0.f);
        *reinterpret_cast<float4*>(out + base + (size_t)d * cstride) = r;
    }
}

// ---- Kernel 4: feature broadcast (unchanged, proven ~4.9 TB/s) ----
__global__ __launch_bounds__(256) void k_feat(
    const float* __restrict__ features, float* __restrict__ out)
{
    const int t = blockIdx.x * 256 + threadIdx.x;   // 0 .. B*D*N - 1
    const float f = features[t];
    const int bd = t >> 15;
    const int n = t & (NN - 1);
    const int b = bd >> 6;
    const int d = bd & (DD - 1);
    const size_t base = (((size_t)b * 2 * DD + DD + d) * NN + n) * KK;
    const float4 v{f, f, f, f};
    float4* p = reinterpret_cast<float4*>(out + base);
    p[0] = v; p[1] = v; p[2] = v; p[3] = v;
}

// ---- launch ----
extern "C" void kernel_launch(void* const* d_in, const int* in_sizes, int n_in,
                              void* d_out, int out_size, void* d_ws, size_t ws_size,
                              hipStream_t stream) {
    const float* coords   = (const float*)d_in[0];
    const float* features = (const float*)d_in[1];
    const float* dist     = (const float*)d_in[2];
    const float* conv_w   = (const float*)d_in[3];
    const float* conv_b   = (const float*)d_in[4];
    const float* gamma    = (const float*)d_in[5];
    const float* beta     = (const float*)d_in[6];
    const int*   idx      = (const int*)d_in[7];
    float* out = (float*)d_out;

    float*  partials = (float*)d_ws;                      // 256*65 = 16640 floats
    float*  wfold    = (float*)d_ws + 24576;              // 512 floats
    float4* coords4  = (float4*)((float*)d_ws + 65536);   // 65536 float4 = 1 MiB

    k_coords4<<<BB * NN / 256, 256, 0, stream>>>(coords, coords4);
    k_moments<<<NBLK1, 256, 0, stream>>>(coords4, dist, idx, partials);
    k_finalize<<<1, 320, 0, stream>>>(partials, conv_w, conv_b, gamma, beta,
                                      wfold);
    k_feat<<<(BB * DD * NN) / 256, 256, 0, stream>>>(features, out);
    k_x<<<(DD / DGRP) * BB * NCHUNKS, 256, 0, stream>>>(
        coords4, dist, idx, wfold, out);
}